// Round 1
// 135.959 us; speedup vs baseline: 1.1312x; 1.1312x over previous
//
#include <hip/hip_runtime.h>
#include <math.h>

typedef unsigned short ushortT;
typedef __bf16 bf16x8 __attribute__((ext_vector_type(8)));
typedef float  f32x4  __attribute__((ext_vector_type(4)));

// grade of each multivector component (blade order: 1,e1,e2,e3,e12,e13,e23,e123)
__constant__ int GRADEc[8] = {0,1,1,1,2,2,2,3};

// Compacted slot maps: zero-weight padding slots removed.
// per output component j: feature plane index for each used K-slot
__constant__ int CMAPc[8][7] = {
  {0, 8, 9,10,11, 0, 0},
  {1,12,13,14,15,16,17},
  {2,18,19,20,21,22,23},
  {3,24,25,26,27,28,29},
  {4,30,31,32,33,34,35},
  {5,36,37,38,39,40,41},
  {6,42,43,44,45,46,47},
  {7,48,49,50,51, 0, 0}};
// per output component j: weight plane for each used K-slot
__constant__ int WMAPc[8][7] = {
  {0, 4, 8,14,20, 0, 0},
  {1, 5, 9,10,15,16,21},
  {1, 5, 9,10,15,16,21},
  {1, 5, 9,10,15,16,21},
  {2, 6,11,12,17,18,22},
  {2, 6,11,12,17,18,22},
  {2, 6,11,12,17,18,22},
  {3, 7,13,19,23, 0, 0}};
// split-K=4 slot ranges per (j, ks): start and count (j=0,7 have 5 slots, others 7)
__constant__ int SSTARTc[8][4] = {
  {0,2,3,4},{0,2,4,6},{0,2,4,6},{0,2,4,6},
  {0,2,4,6},{0,2,4,6},{0,2,4,6},{0,2,3,4}};
__constant__ int SCOUNTc[8][4] = {
  {2,1,1,1},{2,2,2,1},{2,2,2,1},{2,2,2,1},
  {2,2,2,1},{2,2,2,1},{2,2,2,1},{2,1,1,1}};

__device__ __forceinline__ ushortT f2bf(float f) {
  unsigned int u = __float_as_uint(f);
  unsigned int r = (u + 0x7fffu + ((u >> 16) & 1u)) >> 16;
  return (ushortT)r;
}

// ---------------- transpose x: x[b][c] (1024 x 2048) -> xT[c][b] ----------------
__global__ void k_transpose_x(const float* __restrict__ x, float* __restrict__ xT) {
  __shared__ float tile[32][33];
  int c0 = blockIdx.x * 32;
  int b0 = blockIdx.y * 32;
  int tx = threadIdx.x & 31, ty = threadIdx.x >> 5;  // 32 x 8
  #pragma unroll
  for (int i = 0; i < 32; i += 8)
    tile[ty + i][tx] = x[(b0 + ty + i) * 2048 + c0 + tx];
  __syncthreads();
  #pragma unroll
  for (int i = 0; i < 32; i += 8)
    xT[(c0 + ty + i) * 1024 + b0 + tx] = tile[tx][ty + i];
}

// ---------------- build WR[g][m][n] = w_right[n][m][g] (fp32) ----------------
__global__ void k_build_wr(const float* __restrict__ w_right, float* __restrict__ WR) {
  int t = blockIdx.x * 256 + threadIdx.x;       // 4*256*256
  int n = t & 255, m = (t >> 8) & 255, g = t >> 16;
  WR[t] = w_right[n * 1024 + m * 4 + g];
}

// ---------------- build WT2b[w][m][n] (bf16): w<4 -> w_left[m][n][w]; w<24 -> gp[m][n][w-4]
__global__ void k_build_wt2(const float* __restrict__ w_left, const float* __restrict__ gp,
                            ushortT* __restrict__ WT2b) {
  int t = blockIdx.x * 256 + threadIdx.x;       // 24*256*256
  int n = t & 255, m = (t >> 8) & 255, w = t >> 16;
  float v;
  if (w < 4)       v = w_left[m * 1024 + n * 4 + w];
  else             v = gp[m * 5120 + n * 20 + (w - 4)];
  WT2b[t] = f2bf(v);
}

// ---------------- right linear: y2[i][b][n] = sum_m xT[m*8+i][b] * WR[g(i)][m][n] ----------
__global__ __launch_bounds__(256) void k_gemm_right2(const float* __restrict__ WR,
                                                     const float* __restrict__ xT,
                                                     float* __restrict__ y2) {
  const int i  = blockIdx.z;
  const int g  = GRADEc[i];
  const int b0 = blockIdx.y * 64;
  const int n0 = blockIdx.x * 64;
  __shared__ float sX[32 * 64];   // [k][b]
  __shared__ float sW[32 * 64];   // [k][n]
  const int t  = threadIdx.x;
  const int tx = t & 15, ty = t >> 4;
  float acc[4][4] = {};
  const float* Xbase = xT + i * 1024 + b0;    // + m*8192 + bb
  const float* Wbase = WR + g * 65536 + n0;   // + m*256  + nn
  for (int k0 = 0; k0 < 256; k0 += 32) {
    int col = t & 63, krow = t >> 6;
    #pragma unroll
    for (int l = 0; l < 8; ++l) {
      int kk = krow + l * 4;
      sX[kk * 64 + col] = Xbase[(k0 + kk) * 8192 + col];
      sW[kk * 64 + col] = Wbase[(k0 + kk) * 256 + col];
    }
    __syncthreads();
    #pragma unroll
    for (int kk = 0; kk < 32; ++kk) {
      const float4 a = *(const float4*)(sX + kk * 64 + (ty << 2));
      const float4 w = *(const float4*)(sW + kk * 64 + (tx << 2));
      float ar[4] = {a.x, a.y, a.z, a.w};
      float wr4[4] = {w.x, w.y, w.z, w.w};
      #pragma unroll
      for (int r = 0; r < 4; ++r)
        #pragma unroll
        for (int c = 0; c < 4; ++c)
          acc[r][c] = fmaf(ar[r], wr4[c], acc[r][c]);
    }
    __syncthreads();
  }
  #pragma unroll
  for (int r = 0; r < 4; ++r) {
    float4 v = make_float4(acc[r][0], acc[r][1], acc[r][2], acc[r][3]);
    *(float4*)(y2 + i * 262144 + (b0 + (ty << 2) + r) * 256 + n0 + (tx << 2)) = v;
  }
}

// ---------------- normalize + features -> FT2b[c][b][n] (bf16) ----------------
__global__ void k_features2(const float* __restrict__ y2, const float* __restrict__ x,
                            const float* __restrict__ norm_a, ushortT* __restrict__ FT2b) {
  const int b = blockIdx.x;
  const int n = threadIdx.x;
  float y[8], xv[8];
  #pragma unroll
  for (int i = 0; i < 8; ++i) y[i] = y2[i * 262144 + b * 256 + n];
  const float4* xp = (const float4*)(x + b * 2048 + n * 8);
  float4 x01 = xp[0], x23 = xp[1];
  xv[0]=x01.x; xv[1]=x01.y; xv[2]=x01.z; xv[3]=x01.w;
  xv[4]=x23.x; xv[5]=x23.y; xv[6]=x23.z; xv[7]=x23.w;
  float4 na = *(const float4*)(norm_a + n * 4);
  float nav[4] = {na.x, na.y, na.z, na.w};
  float nr[4];
  nr[0] = fabsf(y[0]);
  nr[1] = sqrtf(y[1]*y[1] + y[2]*y[2] + y[3]*y[3]);
  nr[2] = sqrtf(y[4]*y[4] + y[5]*y[5] + y[6]*y[6]);
  nr[3] = fabsf(y[7]);
  float inv[4];
  #pragma unroll
  for (int g = 0; g < 4; ++g) {
    float s = 1.0f / (1.0f + expf(-nav[g]));
    inv[g] = 1.0f / (s * (nr[g] - 1.0f) + 1.0f + 1e-6f);
  }
  float r[8];
  r[0] = y[0]*inv[0];
  r[1] = y[1]*inv[1]; r[2] = y[2]*inv[1]; r[3] = y[3]*inv[1];
  r[4] = y[4]*inv[2]; r[5] = y[5]*inv[2]; r[6] = y[6]*inv[2];
  r[7] = y[7]*inv[3];

  float F[52];
  #pragma unroll
  for (int i = 0; i < 8; ++i) F[i] = xv[i];
  F[8]  = xv[0]*r[0];
  F[9]  = xv[1]*r[1] + xv[2]*r[2] + xv[3]*r[3];
  F[10] = -(xv[4]*r[4] + xv[5]*r[5] + xv[6]*r[6]);
  F[11] = -xv[7]*r[7];
  F[12] = xv[0]*r[1];
  F[13] = xv[1]*r[0];
  F[14] = -(xv[2]*r[4] + xv[3]*r[5]);
  F[15] = xv[4]*r[2] + xv[5]*r[3];
  F[16] = -xv[6]*r[7];
  F[17] = -xv[7]*r[6];
  F[18] = xv[0]*r[2];
  F[19] = xv[2]*r[0];
  F[20] = xv[1]*r[4] - xv[3]*r[6];
  F[21] = -xv[4]*r[1] + xv[6]*r[3];
  F[22] = xv[5]*r[7];
  F[23] = xv[7]*r[5];
  F[24] = xv[0]*r[3];
  F[25] = xv[3]*r[0];
  F[26] = xv[1]*r[5] + xv[2]*r[6];
  F[27] = -(xv[5]*r[1] + xv[6]*r[2]);
  F[28] = -xv[4]*r[7];
  F[29] = -xv[7]*r[4];
  F[30] = xv[0]*r[4];
  F[31] = xv[1]*r[2] - xv[2]*r[1];
  F[32] = xv[3]*r[7];
  F[33] = xv[4]*r[0];
  F[34] = -xv[5]*r[6] + xv[6]*r[5];
  F[35] = xv[7]*r[3];
  F[36] = xv[0]*r[5];
  F[37] = xv[1]*r[3] - xv[3]*r[1];
  F[38] = -xv[2]*r[7];
  F[39] = xv[5]*r[0];
  F[40] = xv[4]*r[6] - xv[6]*r[4];
  F[41] = -xv[7]*r[2];
  F[42] = xv[0]*r[6];
  F[43] = xv[2]*r[3] - xv[3]*r[2];
  F[44] = xv[1]*r[7];
  F[45] = xv[6]*r[0];
  F[46] = -xv[4]*r[5] + xv[5]*r[4];
  F[47] = xv[7]*r[1];
  F[48] = xv[0]*r[7];
  F[49] = xv[1]*r[6] - xv[2]*r[5] + xv[3]*r[4];
  F[50] = xv[4]*r[3] - xv[5]*r[2] + xv[6]*r[1];
  F[51] = xv[7]*r[0];

  #pragma unroll
  for (int c = 0; c < 52; ++c)
    FT2b[c * 262144 + b * 256 + n] = f2bf(F[c]);
}

// ---------------- main GEMM (MFMA bf16): outP[ks][j][b][m] = A_j[b][k] * B_j[k][m] ----------------
// K = slot*256 + n (slot-major, compacted slots). A_j plane: FT2b[CMAP[j][slot]][b][n];
// B_j: WT2b[WMAP[j][slot]][m][n]. Each split-K quarter writes its PRIVATE partial buffer:
// plain stores, no atomics, no memset needed.
__global__ __launch_bounds__(256) void k_gemm_mfma(const ushortT* __restrict__ FT2b,
                                                   const ushortT* __restrict__ WT2b,
                                                   float* __restrict__ outP) {
  const int j  = blockIdx.z >> 2;
  const int ks = blockIdx.z & 3;          // split-K quarter
  const int b0 = blockIdx.y * 128;
  const int m0 = blockIdx.x * 128;
  __shared__ ushortT sA[128 * 40];        // rows b, 32 n + 8 pad
  __shared__ ushortT sB[128 * 40];        // rows m, 32 n + 8 pad
  const int t    = threadIdx.x;
  const int wave = t >> 6;
  const int lane = t & 63;
  const int wb   = (wave & 1) * 64;
  const int wm   = (wave >> 1) * 64;
  const int lrow = lane & 15;
  const int lkg  = lane >> 4;

  f32x4 acc[4][4];
  #pragma unroll
  for (int r = 0; r < 4; ++r)
    #pragma unroll
    for (int c = 0; c < 4; ++c)
      acc[r][c] = (f32x4){0.f, 0.f, 0.f, 0.f};

  const int row0 = t >> 2, seg0 = t & 3;          // staging: 2 reps of 16B each
  const int row1 = (t + 256) >> 2, seg1 = t & 3;

  const int sstart = SSTARTc[j][ks];
  const int scnt   = SCOUNTc[j][ks];
  for (int s2 = 0; s2 < scnt; ++s2) {
    const int slot = sstart + s2;
    const ushortT* Ap = FT2b + CMAPc[j][slot] * 262144 + b0 * 256;
    const ushortT* Bp = WT2b + WMAPc[j][slot] * 65536 + m0 * 256;
    for (int n0 = 0; n0 < 256; n0 += 32) {
      uint4 va0 = *(const uint4*)(Ap + row0 * 256 + n0 + seg0 * 8);
      uint4 vb0 = *(const uint4*)(Bp + row0 * 256 + n0 + seg0 * 8);
      uint4 va1 = *(const uint4*)(Ap + row1 * 256 + n0 + seg1 * 8);
      uint4 vb1 = *(const uint4*)(Bp + row1 * 256 + n0 + seg1 * 8);
      *(uint4*)(sA + row0 * 40 + seg0 * 8) = va0;
      *(uint4*)(sB + row0 * 40 + seg0 * 8) = vb0;
      *(uint4*)(sA + row1 * 40 + seg1 * 8) = va1;
      *(uint4*)(sB + row1 * 40 + seg1 * 8) = vb1;
      __syncthreads();
      bf16x8 af[4], bf[4];
      #pragma unroll
      for (int r = 0; r < 4; ++r)
        af[r] = *(const bf16x8*)(sA + (wb + r * 16 + lrow) * 40 + lkg * 8);
      #pragma unroll
      for (int c = 0; c < 4; ++c)
        bf[c] = *(const bf16x8*)(sB + (wm + c * 16 + lrow) * 40 + lkg * 8);
      #pragma unroll
      for (int r = 0; r < 4; ++r)
        #pragma unroll
        for (int c = 0; c < 4; ++c)
          acc[r][c] = __builtin_amdgcn_mfma_f32_16x16x32_bf16(af[r], bf[c], acc[r][c], 0, 0, 0);
      __syncthreads();
    }
  }

  float* oj = outP + (ks * 8 + j) * 262144;
  #pragma unroll
  for (int r = 0; r < 4; ++r) {
    #pragma unroll
    for (int c = 0; c < 4; ++c) {
      #pragma unroll
      for (int e = 0; e < 4; ++e) {
        int brow = b0 + wb + r * 16 + lkg * 4 + e;
        int mcol = m0 + wm + c * 16 + lrow;
        oj[brow * 256 + mcol] = acc[r][c][e];
      }
    }
  }
}

// ---------------- merge: out[b][m][j] = (sum_ks outP[ks][j][b][m] + bias_j) * 1/sqrt(2) ----------------
__global__ void k_merge(const float* __restrict__ outP, const float* __restrict__ bleft,
                        float* __restrict__ out) {
  const int idx = blockIdx.x * 256 + threadIdx.x;   // over b*m = 262144
  const int m = idx & 255;
  const float bias = bleft[m];
  const float sc = 0.7071067811865475f;
  float o[8];
  #pragma unroll
  for (int jj = 0; jj < 8; ++jj) {
    float s = 0.0f;
    #pragma unroll
    for (int p = 0; p < 4; ++p)
      s += outP[(p * 8 + jj) * 262144 + idx];
    o[jj] = s;
  }
  o[0] += bias;
  float4 v0 = make_float4(o[0]*sc, o[1]*sc, o[2]*sc, o[3]*sc);
  float4 v1 = make_float4(o[4]*sc, o[5]*sc, o[6]*sc, o[7]*sc);
  *(float4*)(out + idx * 8)     = v0;
  *(float4*)(out + idx * 8 + 4) = v1;
}

extern "C" void kernel_launch(void* const* d_in, const int* in_sizes, int n_in,
                              void* d_out, int out_size, void* d_ws, size_t ws_size,
                              hipStream_t stream) {
  const float* x       = (const float*)d_in[0];
  const float* w_right = (const float*)d_in[1];
  const float* w_left  = (const float*)d_in[2];
  const float* b_left  = (const float*)d_in[3];
  const float* norm_a  = (const float*)d_in[4];
  const float* gp      = (const float*)d_in[5];
  float* out = (float*)d_out;
  float* W   = (float*)d_ws;

  // ws layout (float offsets)
  float*   xT   = W;                          // 2,097,152 floats
  float*   WR   = W + 2097152;                //   262,144
  float*   y2   = W + 2359296;                // 2,097,152
  float*   outP = W + 4456448;                // 8,388,608 (4 split-K partial planes)
  ushortT* FT2b = (ushortT*)(W + 12845056);   // 13,631,488 ushort (6,815,744 floats)
  ushortT* WT2b = (ushortT*)(W + 19660800);   //  1,638,400 ushort (  819,200 floats)

  k_transpose_x<<<dim3(64, 32), 256, 0, stream>>>(x, xT);
  k_build_wr<<<1024, 256, 0, stream>>>(w_right, WR);
  k_build_wt2<<<6144, 256, 0, stream>>>(w_left, gp, WT2b);
  k_gemm_right2<<<dim3(4, 16, 8), 256, 0, stream>>>(WR, xT, y2);
  k_features2<<<1024, 256, 0, stream>>>(y2, x, norm_a, FT2b);
  k_gemm_mfma<<<dim3(2, 8, 32), 256, 0, stream>>>(FT2b, WT2b, outP);
  k_merge<<<1024, 256, 0, stream>>>(outP, b_left, out);
}

// Round 2
// 120.953 us; speedup vs baseline: 1.2715x; 1.1241x over previous
//
#include <hip/hip_runtime.h>
#include <math.h>

typedef unsigned short ushortT;
typedef __bf16 bf16x8 __attribute__((ext_vector_type(8)));
typedef float  f32x4  __attribute__((ext_vector_type(4)));

// grade of each multivector component (blade order: 1,e1,e2,e3,e12,e13,e23,e123)
__constant__ int GRADEc[8] = {0,1,1,1,2,2,2,3};

// Compacted slot maps: zero-weight padding slots removed.
// per output component j: feature plane index for each used K-slot
__constant__ int CMAPc[8][7] = {
  {0, 8, 9,10,11, 0, 0},
  {1,12,13,14,15,16,17},
  {2,18,19,20,21,22,23},
  {3,24,25,26,27,28,29},
  {4,30,31,32,33,34,35},
  {5,36,37,38,39,40,41},
  {6,42,43,44,45,46,47},
  {7,48,49,50,51, 0, 0}};
// per output component j: weight plane for each used K-slot
__constant__ int WMAPc[8][7] = {
  {0, 4, 8,14,20, 0, 0},
  {1, 5, 9,10,15,16,21},
  {1, 5, 9,10,15,16,21},
  {1, 5, 9,10,15,16,21},
  {2, 6,11,12,17,18,22},
  {2, 6,11,12,17,18,22},
  {2, 6,11,12,17,18,22},
  {3, 7,13,19,23, 0, 0}};
// split-K=4 slot ranges per (j, ks)
__constant__ int SSTARTc[8][4] = {
  {0,2,3,4},{0,2,4,6},{0,2,4,6},{0,2,4,6},
  {0,2,4,6},{0,2,4,6},{0,2,4,6},{0,2,3,4}};
__constant__ int SCOUNTc[8][4] = {
  {2,1,1,1},{2,2,2,1},{2,2,2,1},{2,2,2,1},
  {2,2,2,1},{2,2,2,1},{2,2,2,1},{2,1,1,1}};

__device__ __forceinline__ ushortT f2bf(float f) {
  unsigned int u = __float_as_uint(f);
  unsigned int r = (u + 0x7fffu + ((u >> 16) & 1u)) >> 16;
  return (ushortT)r;
}

// async global->LDS 16B DMA: dest = wave-uniform base + lane*16 (linear), source per-lane.
#define GLOAD_LDS16(gsrc, ldst) \
  __builtin_amdgcn_global_load_lds((const __attribute__((address_space(1))) unsigned int*)(gsrc), \
                                   (__attribute__((address_space(3))) unsigned int*)(ldst), 16, 0, 0)

// ---------------- split x into bf16 hi/lo planes: XH/XL[i][b][m] = split(x[b][m*8+i]) --------
__global__ void k_xsplit(const float* __restrict__ x, ushortT* __restrict__ XH,
                         ushortT* __restrict__ XL) {
  const int b = blockIdx.x;
  const int m = threadIdx.x;
  const float4* xp = (const float4*)(x + b * 2048 + m * 8);
  float4 a = xp[0], c = xp[1];
  float v[8] = {a.x, a.y, a.z, a.w, c.x, c.y, c.z, c.w};
  #pragma unroll
  for (int i = 0; i < 8; ++i) {
    ushortT h = f2bf(v[i]);
    float hf = __uint_as_float(((unsigned int)h) << 16);
    XH[i * 262144 + b * 256 + m] = h;
    XL[i * 262144 + b * 256 + m] = f2bf(v[i] - hf);
  }
}

// ---------------- split w_right into bf16 hi/lo planes: WH/WL[g][n][m] = split(w_right[n][m][g])
__global__ void k_wsplit(const float* __restrict__ w_right, ushortT* __restrict__ WH,
                         ushortT* __restrict__ WL) {
  const int n = blockIdx.x;
  const int m = threadIdx.x;
  float4 w = *(const float4*)(w_right + n * 1024 + m * 4);
  float v[4] = {w.x, w.y, w.z, w.w};
  #pragma unroll
  for (int g = 0; g < 4; ++g) {
    ushortT h = f2bf(v[g]);
    float hf = __uint_as_float(((unsigned int)h) << 16);
    WH[g * 65536 + n * 256 + m] = h;
    WL[g * 65536 + n * 256 + m] = f2bf(v[g] - hf);
  }
}

// ---------------- build WT2b[w][m][n] (bf16): w<4 -> w_left[m][n][w]; w<24 -> gp[m][n][w-4]
__global__ void k_build_wt2(const float* __restrict__ w_left, const float* __restrict__ gp,
                            ushortT* __restrict__ WT2b) {
  int t = blockIdx.x * 256 + threadIdx.x;       // 24*256*256
  int n = t & 255, m = (t >> 8) & 255, w = t >> 16;
  float v;
  if (w < 4)       v = w_left[m * 1024 + n * 4 + w];
  else             v = gp[m * 5120 + n * 20 + (w - 4)];
  WT2b[t] = f2bf(v);
}

// ---------------- right linear via MFMA, 3-term bf16 split ----------------
// y2[i][b][n] = sum_m x[b][m*8+i]*w_right[n][m][g(i)]  ~=  Ah*Bh + Al*Bh + Ah*Bl
// A rows=b (k=m contig), B rows=n (k=m contig). 64x64 tile, 4 waves, each 32x32.
__global__ __launch_bounds__(256) void k_right_mfma(const ushortT* __restrict__ XH,
                                                    const ushortT* __restrict__ XL,
                                                    const ushortT* __restrict__ WH,
                                                    const ushortT* __restrict__ WL,
                                                    float* __restrict__ y2) {
  const int i  = blockIdx.z;
  const int g  = GRADEc[i];
  const int b0 = blockIdx.y * 64;
  const int n0 = blockIdx.x * 64;
  // 4 planes (Ah, Al, Bh, Bl), each [64 rows][32 k] linear (row stride 64B), XOR-swizzled segs
  __shared__ __align__(16) ushortT lds[4 * 2048];
  const int t = threadIdx.x;
  const int wave = t >> 6, lane = t & 63;
  const int wb = (wave & 1) * 32, wn = (wave >> 1) * 32;
  const int lrow = lane & 15, lkg = lane >> 4;

  const ushortT* Ah = XH + i * 262144 + b0 * 256;
  const ushortT* Al = XL + i * 262144 + b0 * 256;
  const ushortT* Bh = WH + g * 65536 + n0 * 256;
  const ushortT* Bl = WL + g * 65536 + n0 * 256;
  // wave w stages plane w (uniform select, no runtime-indexed array -> no scratch)
  const ushortT* gp0 = (wave == 0) ? Ah : (wave == 1) ? Al : (wave == 2) ? Bh : Bl;
  ushortT* lbase = lds + wave * 2048;

  const int srow = lane >> 2;     // 0..15 within instr
  const int sseg = lane & 3;      // phys seg

  f32x4 acc[2][2];
  #pragma unroll
  for (int r = 0; r < 2; ++r)
    #pragma unroll
    for (int c = 0; c < 2; ++c)
      acc[r][c] = (f32x4){0.f, 0.f, 0.f, 0.f};

  for (int k0 = 0; k0 < 256; k0 += 32) {
    #pragma unroll
    for (int q = 0; q < 4; ++q) {
      int row = q * 16 + srow;                       // 0..63
      int slog = sseg ^ ((row >> 1) & 3);
      GLOAD_LDS16(gp0 + row * 256 + k0 + slog * 8, lbase + q * 512);
    }
    __syncthreads();
    bf16x8 afh[2], afl[2], bfh[2], bfl[2];
    #pragma unroll
    for (int r = 0; r < 2; ++r) {
      int row = wb + r * 16 + lrow;
      int po = row * 32 + (lkg ^ ((row >> 1) & 3)) * 8;
      afh[r] = *(const bf16x8*)(lds + po);
      afl[r] = *(const bf16x8*)(lds + 2048 + po);
    }
    #pragma unroll
    for (int c = 0; c < 2; ++c) {
      int row = wn + c * 16 + lrow;
      int po = row * 32 + (lkg ^ ((row >> 1) & 3)) * 8;
      bfh[c] = *(const bf16x8*)(lds + 4096 + po);
      bfl[c] = *(const bf16x8*)(lds + 6144 + po);
    }
    #pragma unroll
    for (int r = 0; r < 2; ++r)
      #pragma unroll
      for (int c = 0; c < 2; ++c) {
        acc[r][c] = __builtin_amdgcn_mfma_f32_16x16x32_bf16(afh[r], bfh[c], acc[r][c], 0, 0, 0);
        acc[r][c] = __builtin_amdgcn_mfma_f32_16x16x32_bf16(afl[r], bfh[c], acc[r][c], 0, 0, 0);
        acc[r][c] = __builtin_amdgcn_mfma_f32_16x16x32_bf16(afh[r], bfl[c], acc[r][c], 0, 0, 0);
      }
    __syncthreads();
  }

  #pragma unroll
  for (int r = 0; r < 2; ++r)
    #pragma unroll
    for (int c = 0; c < 2; ++c)
      #pragma unroll
      for (int e = 0; e < 4; ++e) {
        int brow = b0 + wb + r * 16 + lkg * 4 + e;
        int ncol = n0 + wn + c * 16 + lrow;
        y2[i * 262144 + brow * 256 + ncol] = acc[r][c][e];
      }
}

// ---------------- normalize + features -> FT2b[c][b][n] (bf16), planes 8..51 only ----------
// (planes 0..7 are bf16(x) == XH planes; main GEMM reads XH for slot 0)
__global__ void k_features2(const float* __restrict__ y2, const float* __restrict__ x,
                            const float* __restrict__ norm_a, ushortT* __restrict__ FT2b) {
  const int b = blockIdx.x;
  const int n = threadIdx.x;
  float y[8], xv[8];
  #pragma unroll
  for (int i = 0; i < 8; ++i) y[i] = y2[i * 262144 + b * 256 + n];
  const float4* xp = (const float4*)(x + b * 2048 + n * 8);
  float4 x01 = xp[0], x23 = xp[1];
  xv[0]=x01.x; xv[1]=x01.y; xv[2]=x01.z; xv[3]=x01.w;
  xv[4]=x23.x; xv[5]=x23.y; xv[6]=x23.z; xv[7]=x23.w;
  float4 na = *(const float4*)(norm_a + n * 4);
  float nav[4] = {na.x, na.y, na.z, na.w};
  float nr[4];
  nr[0] = fabsf(y[0]);
  nr[1] = sqrtf(y[1]*y[1] + y[2]*y[2] + y[3]*y[3]);
  nr[2] = sqrtf(y[4]*y[4] + y[5]*y[5] + y[6]*y[6]);
  nr[3] = fabsf(y[7]);
  float inv[4];
  #pragma unroll
  for (int g = 0; g < 4; ++g) {
    float s = 1.0f / (1.0f + expf(-nav[g]));
    inv[g] = 1.0f / (s * (nr[g] - 1.0f) + 1.0f + 1e-6f);
  }
  float r[8];
  r[0] = y[0]*inv[0];
  r[1] = y[1]*inv[1]; r[2] = y[2]*inv[1]; r[3] = y[3]*inv[1];
  r[4] = y[4]*inv[2]; r[5] = y[5]*inv[2]; r[6] = y[6]*inv[2];
  r[7] = y[7]*inv[3];

  float F[52];
  F[8]  = xv[0]*r[0];
  F[9]  = xv[1]*r[1] + xv[2]*r[2] + xv[3]*r[3];
  F[10] = -(xv[4]*r[4] + xv[5]*r[5] + xv[6]*r[6]);
  F[11] = -xv[7]*r[7];
  F[12] = xv[0]*r[1];
  F[13] = xv[1]*r[0];
  F[14] = -(xv[2]*r[4] + xv[3]*r[5]);
  F[15] = xv[4]*r[2] + xv[5]*r[3];
  F[16] = -xv[6]*r[7];
  F[17] = -xv[7]*r[6];
  F[18] = xv[0]*r[2];
  F[19] = xv[2]*r[0];
  F[20] = xv[1]*r[4] - xv[3]*r[6];
  F[21] = -xv[4]*r[1] + xv[6]*r[3];
  F[22] = xv[5]*r[7];
  F[23] = xv[7]*r[5];
  F[24] = xv[0]*r[3];
  F[25] = xv[3]*r[0];
  F[26] = xv[1]*r[5] + xv[2]*r[6];
  F[27] = -(xv[5]*r[1] + xv[6]*r[2]);
  F[28] = -xv[4]*r[7];
  F[29] = -xv[7]*r[4];
  F[30] = xv[0]*r[4];
  F[31] = xv[1]*r[2] - xv[2]*r[1];
  F[32] = xv[3]*r[7];
  F[33] = xv[4]*r[0];
  F[34] = -xv[5]*r[6] + xv[6]*r[5];
  F[35] = xv[7]*r[3];
  F[36] = xv[0]*r[5];
  F[37] = xv[1]*r[3] - xv[3]*r[1];
  F[38] = -xv[2]*r[7];
  F[39] = xv[5]*r[0];
  F[40] = xv[4]*r[6] - xv[6]*r[4];
  F[41] = -xv[7]*r[2];
  F[42] = xv[0]*r[6];
  F[43] = xv[2]*r[3] - xv[3]*r[2];
  F[44] = xv[1]*r[7];
  F[45] = xv[6]*r[0];
  F[46] = -xv[4]*r[5] + xv[5]*r[4];
  F[47] = xv[7]*r[1];
  F[48] = xv[0]*r[7];
  F[49] = xv[1]*r[6] - xv[2]*r[5] + xv[3]*r[4];
  F[50] = xv[4]*r[3] - xv[5]*r[2] + xv[6]*r[1];
  F[51] = xv[7]*r[0];

  #pragma unroll
  for (int c = 8; c < 52; ++c)
    FT2b[c * 262144 + b * 256 + n] = f2bf(F[c]);
}

// ---------------- main GEMM (MFMA bf16): outP[ks][j][b][m] = A_j[b][k] * B_j[k][m] ----------
// K-chunk = 64, staged via global_load_lds (linear LDS [128][64], XOR-swizzled 16B segs:
// phys_seg = log_seg ^ (row&7); inverse applied on global source, forward on ds_read).
__global__ __launch_bounds__(256) void k_gemm_mfma(const ushortT* __restrict__ XH,
                                                   const ushortT* __restrict__ FT2b,
                                                   const ushortT* __restrict__ WT2b,
                                                   float* __restrict__ outP) {
  const int j  = blockIdx.z >> 2;
  const int ks = blockIdx.z & 3;          // split-K quarter
  const int b0 = blockIdx.y * 128;
  const int m0 = blockIdx.x * 128;
  __shared__ __align__(16) ushortT sA[128 * 64];
  __shared__ __align__(16) ushortT sB[128 * 64];
  const int t    = threadIdx.x;
  const int wave = t >> 6;
  const int lane = t & 63;
  const int wb   = (wave & 1) * 64;
  const int wm   = (wave >> 1) * 64;
  const int lrow = lane & 15;
  const int lkg  = lane >> 4;
  const int srow = lane >> 3;             // 0..7 within staging instr
  const int sseg = lane & 7;              // phys seg

  f32x4 acc[4][4];
  #pragma unroll
  for (int r = 0; r < 4; ++r)
    #pragma unroll
    for (int c = 0; c < 4; ++c)
      acc[r][c] = (f32x4){0.f, 0.f, 0.f, 0.f};

  const int sstart = SSTARTc[j][ks];
  const int scnt   = SCOUNTc[j][ks];
  for (int s2 = 0; s2 < scnt; ++s2) {
    const int slot = sstart + s2;
    const ushortT* Ap = ((slot == 0) ? (XH + j * 262144)
                                     : (FT2b + CMAPc[j][slot] * 262144)) + b0 * 256;
    const ushortT* Bp = WT2b + WMAPc[j][slot] * 65536 + m0 * 256;
    for (int k0 = 0; k0 < 256; k0 += 64) {
      #pragma unroll
      for (int q = 0; q < 4; ++q) {
        int idx = wave * 4 + q;                      // staging instr 0..15
        int row = idx * 8 + srow;                    // 0..127
        int slog = sseg ^ (row & 7);
        GLOAD_LDS16(Ap + row * 256 + k0 + slog * 8, sA + idx * 512);
        GLOAD_LDS16(Bp + row * 256 + k0 + slog * 8, sB + idx * 512);
      }
      __syncthreads();
      #pragma unroll
      for (int kk = 0; kk < 2; ++kk) {
        bf16x8 af[4], bf[4];
        #pragma unroll
        for (int r = 0; r < 4; ++r) {
          int row = wb + r * 16 + lrow;
          af[r] = *(const bf16x8*)(sA + row * 64 + (((kk * 4 + lkg) ^ (row & 7)) * 8));
        }
        #pragma unroll
        for (int c = 0; c < 4; ++c) {
          int row = wm + c * 16 + lrow;
          bf[c] = *(const bf16x8*)(sB + row * 64 + (((kk * 4 + lkg) ^ (row & 7)) * 8));
        }
        #pragma unroll
        for (int r = 0; r < 4; ++r)
          #pragma unroll
          for (int c = 0; c < 4; ++c)
            acc[r][c] = __builtin_amdgcn_mfma_f32_16x16x32_bf16(af[r], bf[c], acc[r][c], 0, 0, 0);
      }
      __syncthreads();
    }
  }

  float* oj = outP + (ks * 8 + j) * 262144;
  #pragma unroll
  for (int r = 0; r < 4; ++r) {
    #pragma unroll
    for (int c = 0; c < 4; ++c) {
      #pragma unroll
      for (int e = 0; e < 4; ++e) {
        int brow = b0 + wb + r * 16 + lkg * 4 + e;
        int mcol = m0 + wm + c * 16 + lrow;
        oj[brow * 256 + mcol] = acc[r][c][e];
      }
    }
  }
}

// ---------------- merge: out[b][m][j] = (sum_ks outP[ks][j][b][m] + bias_j) * 1/sqrt(2) ------
__global__ void k_merge(const float* __restrict__ outP, const float* __restrict__ bleft,
                        float* __restrict__ out) {
  const int idx = blockIdx.x * 256 + threadIdx.x;   // over b*m = 262144
  const int m = idx & 255;
  const float bias = bleft[m];
  const float sc = 0.7071067811865475f;
  float o[8];
  #pragma unroll
  for (int jj = 0; jj < 8; ++jj) {
    float s = 0.0f;
    #pragma unroll
    for (int p = 0; p < 4; ++p)
      s += outP[(p * 8 + jj) * 262144 + idx];
    o[jj] = s;
  }
  o[0] += bias;
  float4 v0 = make_float4(o[0]*sc, o[1]*sc, o[2]*sc, o[3]*sc);
  float4 v1 = make_float4(o[4]*sc, o[5]*sc, o[6]*sc, o[7]*sc);
  *(float4*)(out + idx * 8)     = v0;
  *(float4*)(out + idx * 8 + 4) = v1;
}

extern "C" void kernel_launch(void* const* d_in, const int* in_sizes, int n_in,
                              void* d_out, int out_size, void* d_ws, size_t ws_size,
                              hipStream_t stream) {
  const float* x       = (const float*)d_in[0];
  const float* w_right = (const float*)d_in[1];
  const float* w_left  = (const float*)d_in[2];
  const float* b_left  = (const float*)d_in[3];
  const float* norm_a  = (const float*)d_in[4];
  const float* gp      = (const float*)d_in[5];
  float* out = (float*)d_out;
  float* W   = (float*)d_ws;

  // ws layout (float offsets)
  float*   y2   = W;                          //  2,097,152 floats
  float*   outP = W + 2097152;                //  8,388,608 (4 split-K partial planes)
  ushortT* XH   = (ushortT*)(W + 10485760);   //  2,097,152 ushort (1,048,576 floats)
  ushortT* XL   = (ushortT*)(W + 11534336);   //  2,097,152 ushort
  ushortT* WH   = (ushortT*)(W + 12582912);   //    262,144 ushort (  131,072 floats)
  ushortT* WL   = (ushortT*)(W + 12713984);   //    262,144 ushort
  ushortT* FT2b = (ushortT*)(W + 12845056);   // 13,631,488 ushort (6,815,744 floats)
  ushortT* WT2b = (ushortT*)(W + 19660800);   //  1,572,864 ushort (  786,432 floats)

  k_xsplit<<<1024, 256, 0, stream>>>(x, XH, XL);
  k_wsplit<<<256, 256, 0, stream>>>(w_right, WH, WL);
  k_build_wt2<<<6144, 256, 0, stream>>>(w_left, gp, WT2b);
  k_right_mfma<<<dim3(4, 16, 8), 256, 0, stream>>>(XH, XL, WH, WL, y2);
  k_features2<<<1024, 256, 0, stream>>>(y2, x, norm_a, FT2b);
  k_gemm_mfma<<<dim3(2, 8, 32), 256, 0, stream>>>(XH, FT2b, WT2b, outP);
  k_merge<<<1024, 256, 0, stream>>>(outP, b_left, out);
}